// Round 6
// baseline (194.504 us; speedup 1.0000x reference)
//
#include <hip/hip_runtime.h>
#include <math.h>

#define NPTS 8192
#define KNN  20
#define NBKT 1024
#define NBLK (NPTS / 64)          // 128 sorted 64-blocks
#define ZLO  (-6.0f)
#define ZSCALE (1024.0f / 12.0f)
#define INVS (12.0f / 1024.0f)    // exact binary

__device__ __forceinline__ int zbucket(float z) {
    int b = (int)floorf((z - ZLO) * ZSCALE);
    return min(max(b, 0), NBKT - 1);
}

// 64-lane bitonic sort, ascending by lane. Keys d, payload ji.
__device__ __forceinline__ void bitonic64(float& d, int& ji, int lane) {
#pragma unroll
    for (int k = 2; k <= 64; k <<= 1) {
#pragma unroll
        for (int j = k >> 1; j > 0; j >>= 1) {
            const float od = __shfl_xor(d, j);
            const int   oi = __shfl_xor(ji, j);
            const bool up      = ((lane & k) == 0);
            const bool lower   = ((lane & j) == 0);
            const bool takeMin = (up == lower);
            const bool sw = takeMin ? (od < d) : (od > d);
            d  = sw ? od : d;
            ji = sw ? oi : ji;
        }
    }
}

// clean a bitonic 64-sequence into ascending order
__device__ __forceinline__ void bitonic_clean64(float& d, int& ji, int lane) {
#pragma unroll
    for (int j = 32; j > 0; j >>= 1) {
        const float od = __shfl_xor(d, j);
        const int   oi = __shfl_xor(ji, j);
        const bool lower = ((lane & j) == 0);
        const bool sw = lower ? (od < d) : (od > d);
        d  = sw ? od : d;
        ji = sw ? oi : ji;
    }
}

// merge LDS hit-pool (cnt entries) into the resident sorted-64 list (ld,lj)
__device__ __forceinline__ void compact(float& ld, int& lj,
                                        const float* __restrict__ sd,
                                        const int* __restrict__ sj,
                                        int cnt, int lane) {
    __builtin_amdgcn_wave_barrier();          // order pool ds_writes before reads
    float bd = (lane < cnt) ? sd[lane] : INFINITY;
    int   bj = (lane < cnt) ? sj[lane] : -1;
    bitonic64(bd, bj, lane);
    const float rd = __shfl(bd, 63 - lane);
    const int   rj = __shfl(bj, 63 - lane);
    const bool sw = rd < ld;
    float md = sw ? rd : ld;
    int   mj = sw ? rj : lj;
    bitonic_clean64(md, mj, lane);
    ld = md; lj = mj;
}

// ---------------- fused prep: xq + z-bucket hist + Wc0/1/2 ----------------
__device__ __forceinline__ void prep_w_elem(const float* __restrict__ W,
                                            float* __restrict__ Wc,
                                            int tid, int O, int C) {
    const int o = tid / C, k = tid % C;
    const float wa = W[o*2*C + k];
    const float wb = W[o*2*C + C + k];
    Wc[o*C + k]       = wa - wb;
    Wc[(O + o)*C + k] = wb;
}

__global__ void prep_all(const float* __restrict__ x,
                         const float* __restrict__ W0,
                         const float* __restrict__ W1,
                         const float* __restrict__ W2,
                         float4* __restrict__ xq,
                         int* __restrict__ bId,
                         int* __restrict__ hist,
                         float* __restrict__ Wc0,
                         float* __restrict__ Wc1,
                         float* __restrict__ Wc2) {
    const int bid = blockIdx.x;
    const int t = threadIdx.x;
    if (bid < 32) {
        const int i = bid * 256 + t;
        const float a = x[3*i+0], b = x[3*i+1], c = x[3*i+2];
        xq[i] = make_float4(a, b, c, 0.0f);
        const int bk = zbucket(c);
        bId[i] = bk;
        atomicAdd(&hist[bk], 1);
    } else if (bid == 32) {
        if (t < 192) prep_w_elem(W0, Wc0, t, 64, 3);
    } else if (bid < 65) {
        prep_w_elem(W1, Wc1, (bid - 33) * 256 + t, 128, 64);
    } else {
        prep_w_elem(W2, Wc2, (bid - 65) * 256 + t, 256, 128);
    }
}

// ---------------- exclusive prefix over 1024 buckets ----------------
__global__ __launch_bounds__(1024) void prefix1024(const int* __restrict__ hist,
                                                   int* __restrict__ start) {
    __shared__ int s[NBKT];
    const int t = threadIdx.x;
    const int v = hist[t];
    s[t] = v;
    __syncthreads();
    for (int off = 1; off < NBKT; off <<= 1) {
        const int u = (t >= off) ? s[t - off] : 0;
        __syncthreads();
        s[t] += u;
        __syncthreads();
    }
    start[t] = s[t] - v;   // exclusive
}

// ---------------- deterministic bucket scatter: 1 wave per bucket ----------------
// Stable by original index (ballot + mbcnt rank within ascending-j batches).
__global__ __launch_bounds__(256) void scatter_kernel(const float4* __restrict__ xq,
                                                      const int* __restrict__ bId,
                                                      const int* __restrict__ start,
                                                      float4* __restrict__ srt) {
    const int lane = threadIdx.x & 63;
    const int w = blockIdx.x * 4 + (threadIdx.x >> 6);   // bucket id 0..1023
    const int base = start[w];
    int cnt = 0;
    for (int jb = 0; jb < NPTS / 64; ++jb) {
        const int j = jb * 64 + lane;
        const bool hit = (bId[j] == w);
        const unsigned long long m = __ballot(hit);
        if (m) {
            const int below = __builtin_amdgcn_mbcnt_hi(
                (unsigned)(m >> 32),
                __builtin_amdgcn_mbcnt_lo((unsigned)m, 0));
            if (hit) {
                float4 v = xq[j];
                v.w = __int_as_float(j);
                srt[base + cnt + below] = v;
            }
            cnt += __popcll(m);
        }
    }
}

// ---------------- KNN: bounded two-sided sweep over z-sorted points ----------------
// 1 query/wave (wave = sorted position s). Start at own 64-block, expand
// left/right; a side dies when its analytic z-bound^2 > cm (cm only
// decreases -> dead stays dead; exact pruning). Pool+compact as R5.
// Top-21 incl self (d=0 -> lane 0); output lanes 1..20.
__global__ __launch_bounds__(256) void knn_sweep(const float4* __restrict__ srt,
                                                 int* __restrict__ idx_out) {
    __shared__ float sdp[4][64];
    __shared__ int   sjp[4][64];
    const int lane = threadIdx.x & 63;
    const int wv   = threadIdx.x >> 6;
    const int s    = blockIdx.x * 4 + wv;     // sorted position of query
    float* sd = sdp[wv];
    int*   sj = sjp[wv];

    const float4 me = srt[s];                 // uniform broadcast load
    const int qorig = __float_as_int(me.w);
    const float zq = me.z;
    const int bq = s >> 6;

    // init from own block (contains self, d=0)
    {
        const float4 c = srt[bq * 64 + lane];
        const float dx = me.x - c.x, dy = me.y - c.y, dz = me.z - c.z;
        float d = dx*dx + dy*dy + dz*dz;
        int j = __float_as_int(c.w);
        bitonic64(d, j, lane);
        // stash into registers named ld/lj below
        sd[lane] = d; sj[lane] = j;   // reuse pool slots transiently (wave-local)
    }
    __builtin_amdgcn_wave_barrier();
    float ld = sd[lane];
    int   lj = sj[lane];
    float cm = __shfl(ld, KNN);               // 21st incl self = 20th excl
    int cnt = 0;

    int left = bq - 1, right = bq + 1;
    bool lal = (left >= 0), ral = (right < NBLK);
    while (lal || ral) {
        float dl = INFINITY, dr = INFINITY;
        if (lal) {
            const float ze = srt[left * 64 + 63].z;          // largest-bucket elem on left
            const int be = zbucket(ze);
            const float hi = (be >= NBKT - 1) ? INFINITY
                             : (ZLO + (float)(be + 1) * INVS + 1e-4f);
            dl = fmaxf(zq - hi, 0.0f);
            if (dl * dl > cm) { lal = false; dl = INFINITY; }
        }
        if (ral) {
            const float ze = srt[right * 64].z;              // smallest-bucket elem on right
            const int be = zbucket(ze);
            const float lo = (be <= 0) ? -INFINITY
                             : (ZLO + (float)be * INVS - 1e-4f);
            dr = fmaxf(lo - zq, 0.0f);
            if (dr * dr > cm) { ral = false; dr = INFINITY; }
        }
        if (!lal && !ral) break;
        int blk;
        if (dl <= dr) { blk = left;  --left;  lal = (left >= 0); }
        else          { blk = right; ++right; ral = (right < NBLK); }

        const float4 pc = srt[blk * 64 + lane];
        const float dx = me.x - pc.x, dy = me.y - pc.y, dz = me.z - pc.z;
        const float d = dx*dx + dy*dy + dz*dz;
        const bool hit = d < cm;
        const unsigned long long m = __ballot(hit);
        if (m) {
            const int tot = __popcll(m);
            if (cnt + tot > 64) {
                compact(ld, lj, sd, sj, cnt, lane);
                cm = __shfl(ld, KNN);
                cnt = 0;
            }
            const int below = __builtin_amdgcn_mbcnt_hi(
                (unsigned)(m >> 32),
                __builtin_amdgcn_mbcnt_lo((unsigned)m, 0));
            if (hit) { sd[cnt + below] = d; sj[cnt + below] = __float_as_int(pc.w); }
            cnt += tot;
        }
    }
    if (cnt > 0) compact(ld, lj, sd, sj, cnt, lane);

    if (lane >= 1 && lane <= KNN) idx_out[qorig * KNN + lane - 1] = lj;
}

// ---------------- layer0 GEMM: K=3 special case ----------------
__global__ __launch_bounds__(128) void gemm0_kernel(const float* __restrict__ x,
                                                    const float* __restrict__ Wc,
                                                    float* __restrict__ T) {
    __shared__ float sw[384];
    const int t = threadIdx.x;
    sw[t]       = Wc[t];
    sw[t + 128] = Wc[t + 128];
    sw[t + 256] = Wc[t + 256];
    __syncthreads();
    const int n = blockIdx.x;
    const float x0 = x[3*n+0], x1 = x[3*n+1], x2 = x[3*n+2];
    T[n*128 + t] = x0*sw[3*t+0] + x1*sw[3*t+1] + x2*sw[3*t+2];
}

// ---------------- fp32 GEMM: T = H (NxK) * W^T (MxK) ----------------
#define BK 16
__global__ __launch_bounds__(256) void gemm_nt(const float* __restrict__ H,
                                               const float* __restrict__ W,
                                               float* __restrict__ T,
                                               int Kk, int Mm) {
    __shared__ float sH[BK][132];
    __shared__ float sW[BK][68];
    const int t  = threadIdx.x;
    const int rg = t & 15;
    const int cg = t >> 4;
    const int row0 = blockIdx.x * 128;
    const int col0 = blockIdx.y * 64;

    const int ar = t >> 2;
    const int ac = t & 3;

    float acc[8][4];
#pragma unroll
    for (int r = 0; r < 8; ++r)
#pragma unroll
        for (int c = 0; c < 4; ++c) acc[r][c] = 0.0f;

    for (int k0 = 0; k0 < Kk; k0 += BK) {
        const float4 ha = *reinterpret_cast<const float4*>(&H[(row0 + ar)      * Kk + k0 + ac*4]);
        const float4 hb = *reinterpret_cast<const float4*>(&H[(row0 + 64 + ar) * Kk + k0 + ac*4]);
        const float4 wa = *reinterpret_cast<const float4*>(&W[(col0 + ar)      * Kk + k0 + ac*4]);
        __syncthreads();
        sH[ac*4+0][ar]    = ha.x; sH[ac*4+1][ar]    = ha.y; sH[ac*4+2][ar]    = ha.z; sH[ac*4+3][ar]    = ha.w;
        sH[ac*4+0][64+ar] = hb.x; sH[ac*4+1][64+ar] = hb.y; sH[ac*4+2][64+ar] = hb.z; sH[ac*4+3][64+ar] = hb.w;
        sW[ac*4+0][ar]    = wa.x; sW[ac*4+1][ar]    = wa.y; sW[ac*4+2][ar]    = wa.z; sW[ac*4+3][ar]    = wa.w;
        __syncthreads();
#pragma unroll
        for (int kk = 0; kk < BK; ++kk) {
            const float4 a0 = *reinterpret_cast<const float4*>(&sH[kk][rg*4]);
            const float4 a1 = *reinterpret_cast<const float4*>(&sH[kk][64 + rg*4]);
            const float4 bv = *reinterpret_cast<const float4*>(&sW[kk][cg*4]);
            const float arr[8] = {a0.x, a0.y, a0.z, a0.w, a1.x, a1.y, a1.z, a1.w};
            const float bb[4]  = {bv.x, bv.y, bv.z, bv.w};
#pragma unroll
            for (int r = 0; r < 8; ++r)
#pragma unroll
                for (int c = 0; c < 4; ++c)
                    acc[r][c] = fmaf(arr[r], bb[c], acc[r][c]);
        }
    }
#pragma unroll
    for (int r = 0; r < 8; ++r) {
        const int row = (r < 4) ? (rg*4 + r) : (64 + rg*4 + (r - 4));
        *reinterpret_cast<float4*>(&T[(row0 + row)*Mm + col0 + cg*4]) =
            make_float4(acc[r][0], acc[r][1], acc[r][2], acc[r][3]);
    }
}

// ---------------- gather + max + bias + relu ----------------
template<int O>
__global__ __launch_bounds__(256) void maxrelu_kernel(const float* __restrict__ T,
                                                      const int* __restrict__ idx,
                                                      const float* __restrict__ bias,
                                                      float* __restrict__ out) {
    constexpr int PPB = 256 / O;
    constexpr int M2  = 2 * O;
    const int pi = threadIdx.x / O;
    const int o  = threadIdx.x & (O - 1);
    const int i  = blockIdx.x * PPB + pi;
    __shared__ int sidx[PPB * KNN];
    if (threadIdx.x < PPB * KNN)
        sidx[threadIdx.x] = idx[blockIdx.x * PPB * KNN + threadIdx.x];
    __syncthreads();
    const int sb = pi * KNN;
    float m = -INFINITY;
#pragma unroll
    for (int k = 0; k < KNN; ++k)
        m = fmaxf(m, T[sidx[sb + k] * M2 + O + o]);
    const float base = T[i * M2 + o] + bias[o];
    out[i * O + o] = fmaxf(base + m, 0.0f);
}

extern "C" void kernel_launch(void* const* d_in, const int* in_sizes, int n_in,
                              void* d_out, int out_size, void* d_ws, size_t ws_size,
                              hipStream_t stream) {
    const float* x  = (const float*)d_in[0];
    const float* W0 = (const float*)d_in[1];
    const float* b0 = (const float*)d_in[2];
    const float* W1 = (const float*)d_in[3];
    const float* b1 = (const float*)d_in[4];
    const float* W2 = (const float*)d_in[5];
    const float* b2 = (const float*)d_in[6];
    float* out = (float*)d_out;
    char*  ws  = (char*)d_ws;

    int*   idx  = (int*)(ws + 0);                 // 8192*20*4   = 655360
    float* Wc0  = (float*)(ws + 655360);          // 1536
    float* Wc1  = (float*)(ws + 656896);          // 65536
    float* Wc2  = (float*)(ws + 722432);          // 262144
    float* bufA = (float*)(ws + 984576);          // 8192*512*4  = 16777216
    float* bufB = (float*)(ws + 17761792);        // 8192*128*4  = 4194304

    // knn-phase scratch aliases bufA (all dead before gemm0 writes bufA)
    float4* xq     = (float4*)bufA;                       // 128 KB
    float4* sorted = (float4*)((char*)bufA + 131072);     // 128 KB
    int*    bId    = (int*)((char*)bufA + 262144);        // 32 KB
    int*    hist   = (int*)((char*)bufA + 294912);        // 4 KB
    int*    bstart = (int*)((char*)bufA + 299008);        // 4 KB

    hipMemsetAsync(hist, 0, NBKT * sizeof(int), stream);
    prep_all<<<193, 256, 0, stream>>>(x, W0, W1, W2, xq, bId, hist, Wc0, Wc1, Wc2);
    prefix1024<<<1, 1024, 0, stream>>>(hist, bstart);
    scatter_kernel<<<NBKT / 4, 256, 0, stream>>>(xq, bId, bstart, sorted);
    knn_sweep<<<NPTS / 4, 256, 0, stream>>>(sorted, idx);

    gemm0_kernel<<<NPTS, 128, 0, stream>>>(x, Wc0, bufA);
    maxrelu_kernel<64><<<NPTS / 4, 256, 0, stream>>>(bufA, idx, b0, bufB);

    gemm_nt<<<dim3(64, 4), 256, 0, stream>>>(bufB, Wc1, bufA, 64, 256);
    maxrelu_kernel<128><<<NPTS / 2, 256, 0, stream>>>(bufA, idx, b1, bufB);

    gemm_nt<<<dim3(64, 8), 256, 0, stream>>>(bufB, Wc2, bufA, 128, 512);
    maxrelu_kernel<256><<<NPTS, 256, 0, stream>>>(bufA, idx, b2, out);
}